// Round 9
// baseline (47.599 us; speedup 1.0000x reference)
//
#include <hip/hip_runtime.h>
#include <hip/hip_bf16.h>

// Sizes (fixed by the reference)
#define NL 3      // layers
#define NB 128    // batch
#define NO 64     // objects
#define ND 64     // emb dim
#define NQ 32     // preds per pair
#define NP 4032   // 64*63 ordered pairs

typedef __bf16 bf16x8 __attribute__((ext_vector_type(8)));
typedef float  f32x4  __attribute__((ext_vector_type(4)));

__device__ __forceinline__ float sigm(float x) {
  return __builtin_amdgcn_rcpf(1.0f + __expf(-x));
}

__device__ __forceinline__ bf16x8 pack_bf16(const f32x4 a, const f32x4 b) {
  bf16x8 r;
  r[0] = (__bf16)a[0]; r[1] = (__bf16)a[1]; r[2] = (__bf16)a[2]; r[3] = (__bf16)a[3];
  r[4] = (__bf16)b[0]; r[5] = (__bf16)b[1]; r[6] = (__bf16)b[2]; r[7] = (__bf16)b[3];
  return r;
}

// ---------------------------------------------------------------------------
// Kernel 1: precompute (verbatim round 7 — known good).
//   blocks 0..127   : b -> mean, M[l][b][d] = mean.W1c + b1 ; exact e copy
//   blocks 128..151 : (l, dt) -> one 64x16 strip of Ut/Vt via MFMA
// ---------------------------------------------------------------------------
__global__ __launch_bounds__(256) void precomp_k(
    const int* __restrict__ ids, const float* __restrict__ emb,
    const float* __restrict__ W1, const float* __restrict__ b1,
    float* __restrict__ Ut, float* __restrict__ Vt, float* __restrict__ M,
    float* __restrict__ e_out)
{
  const int blk = blockIdx.x, tid = threadIdx.x;

  if (blk < NB) {
    __shared__ int   ids_s[NO];
    __shared__ float psum[4][ND];
    __shared__ float mean_s[ND];
    const int b = blk;
    if (tid < NO) ids_s[tid] = ids[b * NO + tid];
    __syncthreads();

    {
      const int d = tid & 63, ng = tid >> 6;
      float s = 0.f;
#pragma unroll
      for (int nn = 0; nn < 16; ++nn) {
        const int n = ng * 16 + nn;
        const float v = emb[ids_s[n] * ND + d];
        e_out[(b * NO + n) * ND + d] = v;   // exact f32 copy of e
        s += v;
      }
      psum[ng][d] = s;
    }
    __syncthreads();
    if (tid < ND)
      mean_s[tid] = (psum[0][tid] + psum[1][tid] + psum[2][tid] + psum[3][tid]) * (1.0f / 64.0f);
    __syncthreads();

    if (tid < 192) {
      const int l = tid >> 6, d = tid & 63;
      const float* wrow = W1 + (l * ND + d) * 192 + 128;
      float acc = 0.f;
#pragma unroll
      for (int c4 = 0; c4 < 16; ++c4) {
        const f32x4 w = *(const f32x4*)(wrow + c4 * 4);
        const f32x4 m = *(const f32x4*)(&mean_s[c4 * 4]);
        acc += w[0] * m[0] + w[1] * m[1] + w[2] * m[2] + w[3] * m[3];
      }
      M[(l * NB + b) * ND + d] = acc + b1[l * ND + d];
    }
  } else {
    // ---- table blocks: one (l, d-tile) strip per block, one row-tile/wave ----
    const int lane = tid & 63, wave = tid >> 6;
    const int qlo = lane & 15, g = lane >> 4;
    const int idx = blk - NB;            // 0..23
    const int l = idx >> 3, dt = idx & 7;
    const bool isU = (dt < 4);
    const int dcol = (dt & 3) * 16 + qlo;

    const float* arow = emb + (wave * 16 + qlo) * ND;            // A row = object
    const float* brow = W1 + (l * ND + dcol) * 192 + (isU ? 0 : 64);
    f32x4 acc = {0.f, 0.f, 0.f, 0.f};
#pragma unroll
    for (int kh = 0; kh < 2; ++kh) {
      const int k0 = kh * 32 + g * 8;
      const bf16x8 af = pack_bf16(*(const f32x4*)(arow + k0), *(const f32x4*)(arow + k0 + 4));
      const bf16x8 bf = pack_bf16(*(const f32x4*)(brow + k0), *(const f32x4*)(brow + k0 + 4));
      acc = __builtin_amdgcn_mfma_f32_16x16x32_bf16(af, bf, acc, 0, 0, 0);
    }
    float* T = isU ? Ut : Vt;            // D: row(obj) = wave*16+4g+r, col(d) = dcol
#pragma unroll
    for (int r = 0; r < 4; ++r)
      T[(l * NO + wave * 16 + 4 * g + r) * ND + dcol] = acc[r];
  }
}

// ---------------------------------------------------------------------------
// Kernel 2: main. SINGLE CHANGE vs round 7: stream-count reduction.
// grid = 3*128*2 = 768 blocks x 512 threads (8 waves), 32 i-rows per block.
// Wave w: j-tile = w&3, q-half = w>>2. All 8 waves jointly write the SAME
// 8KB i-row per iteration -> ONE sequential 258KB stream per block
// (768 streams vs 1536), at the same 24 waves/CU.
// ---------------------------------------------------------------------------
__global__ __launch_bounds__(512, 6) void main_k(
    const int* __restrict__ ids, const float* __restrict__ W2,
    const float* __restrict__ b2,
    const float* __restrict__ Ut, const float* __restrict__ Vt,
    const float* __restrict__ M, float* __restrict__ out)
{
  __shared__ float UpM_s[32 * 68];

  const int tid = threadIdx.x, blk = blockIdx.x;
  const int ic = blk & 1, b = (blk >> 1) & 127, l = blk >> 8;
  const int lane = tid & 63, wave = tid >> 6;   // 0..7
  const int jw = wave & 3, qh = wave >> 2;      // j-tile, q-half
  const int qlo = lane & 15, g = lane >> 4;
  const int i0 = ic * 32;

  // ---- stage UpM: 32 rows x 64 cols, one f32x4 per thread (512 thr) ----
  {
    const int row = tid >> 4, c0 = (tid & 15) * 4;
    const int idi = ids[b * NO + i0 + row];
    const float* u = Ut + (l * NO + idi) * ND + c0;
    const float* m = M + (l * NB + b) * ND + c0;
    *(f32x4*)(&UpM_s[row * 68 + c0]) = *(const f32x4*)u + *(const f32x4*)m;
  }

  // ---- V (f32), W2 frag (this wave's q-half), b2 into registers ----
  const int jA = jw * 16 + qlo;          // this lane's pair column j (fixed)
  const int idj = ids[b * NO + jA];
  const float* vrow = Vt + (l * NO + idj) * ND;
  f32x4 vf[2][2];
#pragma unroll
  for (int kt = 0; kt < 2; ++kt) {
    vf[kt][0] = *(const f32x4*)(vrow + kt * 32 + g * 8);
    vf[kt][1] = *(const f32x4*)(vrow + kt * 32 + g * 8 + 4);
  }
  bf16x8 wfrag[2];
#pragma unroll
  for (int kt = 0; kt < 2; ++kt) {
    const float* wp = W2 + (l * NQ + qh * 16 + qlo) * ND + kt * 32 + g * 8;
    wfrag[kt] = pack_bf16(*(const f32x4*)wp, *(const f32x4*)(wp + 4));
  }
  const f32x4 b2v = *(const f32x4*)(b2 + l * NQ + qh * 16 + g * 4);  // q=qh*16+4g+r

  __syncthreads();

  float* outb = out + (size_t)(l * NB + b) * NP * NQ;

  // ---- barrier-free i-loop (unroll 2 for cross-iter ILP) ----
#pragma unroll 2
  for (int ii = 0; ii < 32; ++ii) {
    const float* upm = &UpM_s[ii * 68];
    bf16x8 hb[2];
#pragma unroll
    for (int kt = 0; kt < 2; ++kt) {
      const int k0 = kt * 32 + g * 8;
      const f32x4 r0 = *(const f32x4*)(upm + k0);
      const f32x4 r1 = *(const f32x4*)(upm + k0 + 4);
      f32x4 h0, h1;
#pragma unroll
      for (int e = 0; e < 4; ++e) {
        h0[e] = fmaxf(vf[kt][0][e] + r0[e], 0.0f);
        h1[e] = fmaxf(vf[kt][1][e] + r1[e], 0.0f);
      }
      hb[kt] = pack_bf16(h0, h1);
    }

    const f32x4 z = {0.f, 0.f, 0.f, 0.f};
    // D[row=q (this q-half)][col=j]; lane holds q = qh*16+4g+r, j = jw*16+qlo
    f32x4 acc = __builtin_amdgcn_mfma_f32_16x16x32_bf16(wfrag[0], hb[0], z, 0, 0, 0);
    acc = __builtin_amdgcn_mfma_f32_16x16x32_bf16(wfrag[1], hb[1], acc, 0, 0, 0);

    const int i = i0 + ii;
    if (jA != i) {
      const int p = (jA < i) ? jA : jA - 1;
      float* base = outb + ((size_t)i * 63 + p) * NQ + qh * 16 + g * 4;
      f32x4 o;
#pragma unroll
      for (int r = 0; r < 4; ++r) o[r] = sigm(acc[r] + b2v[r]);
      *(f32x4*)base = o;
    }
  }
}

// ---------------------------------------------------------------------------
extern "C" void kernel_launch(void* const* d_in, const int* in_sizes, int n_in,
                              void* d_out, int out_size, void* d_ws, size_t ws_size,
                              hipStream_t stream) {
  const int*   ids = (const int*)d_in[0];
  const float* emb = (const float*)d_in[1];
  const float* W1  = (const float*)d_in[2];
  const float* b1  = (const float*)d_in[3];
  const float* W2  = (const float*)d_in[4];
  const float* b2  = (const float*)d_in[5];
  float* out = (float*)d_out;

  float* Ut = (float*)d_ws;              // [3][64][64] f32
  float* Vt = Ut + NL * NO * ND;         // [3][64][64] f32
  float* M  = Vt + NL * NO * ND;         // [3][128][64] f32  (192 KB of ws)
  float* e_out = out + (size_t)NL * NB * NP * NQ;  // e appended after preds

  precomp_k<<<NB + 24, 256, 0, stream>>>(ids, emb, W1, b1, Ut, Vt, M, e_out);
  main_k<<<NL * NB * 2, 512, 0, stream>>>(ids, W2, b2, Ut, Vt, M, out);
}

// Round 10
// 43.821 us; speedup vs baseline: 1.0862x; 1.0862x over previous
//
#include <hip/hip_runtime.h>
#include <hip/hip_bf16.h>

// Sizes (fixed by the reference)
#define NL 3      // layers
#define NB 128    // batch
#define NO 64     // objects
#define ND 64     // emb dim
#define NQ 32     // preds per pair
#define NP 4032   // 64*63 ordered pairs

typedef __bf16 bf16x8 __attribute__((ext_vector_type(8)));
typedef float  f32x4  __attribute__((ext_vector_type(4)));

#define NLOG2E (-1.44269504088896341f)   // -log2(e)

__device__ __forceinline__ bf16x8 pack_bf16(const f32x4 a, const f32x4 b) {
  bf16x8 r;
  r[0] = (__bf16)a[0]; r[1] = (__bf16)a[1]; r[2] = (__bf16)a[2]; r[3] = (__bf16)a[3];
  r[4] = (__bf16)b[0]; r[5] = (__bf16)b[1]; r[6] = (__bf16)b[2]; r[7] = (__bf16)b[3];
  return r;
}

// pack with scale (for W2 * -log2e fold)
__device__ __forceinline__ bf16x8 pack_bf16_s(const f32x4 a, const f32x4 b, float s) {
  bf16x8 r;
  r[0] = (__bf16)(a[0]*s); r[1] = (__bf16)(a[1]*s); r[2] = (__bf16)(a[2]*s); r[3] = (__bf16)(a[3]*s);
  r[4] = (__bf16)(b[0]*s); r[5] = (__bf16)(b[1]*s); r[6] = (__bf16)(b[2]*s); r[7] = (__bf16)(b[3]*s);
  return r;
}

// ---------------------------------------------------------------------------
// Kernel 1: precompute (verbatim round 7 — known good).
//   blocks 0..127   : b -> mean, M[l][b][d] = mean.W1c + b1 ; exact e copy
//   blocks 128..151 : (l, dt) -> one 64x16 strip of Ut/Vt via MFMA
// ---------------------------------------------------------------------------
__global__ __launch_bounds__(256) void precomp_k(
    const int* __restrict__ ids, const float* __restrict__ emb,
    const float* __restrict__ W1, const float* __restrict__ b1,
    float* __restrict__ Ut, float* __restrict__ Vt, float* __restrict__ M,
    float* __restrict__ e_out)
{
  const int blk = blockIdx.x, tid = threadIdx.x;

  if (blk < NB) {
    __shared__ int   ids_s[NO];
    __shared__ float psum[4][ND];
    __shared__ float mean_s[ND];
    const int b = blk;
    if (tid < NO) ids_s[tid] = ids[b * NO + tid];
    __syncthreads();

    {
      const int d = tid & 63, ng = tid >> 6;
      float s = 0.f;
#pragma unroll
      for (int nn = 0; nn < 16; ++nn) {
        const int n = ng * 16 + nn;
        const float v = emb[ids_s[n] * ND + d];
        e_out[(b * NO + n) * ND + d] = v;   // exact f32 copy of e
        s += v;
      }
      psum[ng][d] = s;
    }
    __syncthreads();
    if (tid < ND)
      mean_s[tid] = (psum[0][tid] + psum[1][tid] + psum[2][tid] + psum[3][tid]) * (1.0f / 64.0f);
    __syncthreads();

    if (tid < 192) {
      const int l = tid >> 6, d = tid & 63;
      const float* wrow = W1 + (l * ND + d) * 192 + 128;
      float acc = 0.f;
#pragma unroll
      for (int c4 = 0; c4 < 16; ++c4) {
        const f32x4 w = *(const f32x4*)(wrow + c4 * 4);
        const f32x4 m = *(const f32x4*)(&mean_s[c4 * 4]);
        acc += w[0] * m[0] + w[1] * m[1] + w[2] * m[2] + w[3] * m[3];
      }
      M[(l * NB + b) * ND + d] = acc + b1[l * ND + d];
    }
  } else {
    // ---- table blocks: one (l, d-tile) strip per block, one row-tile/wave ----
    const int lane = tid & 63, wave = tid >> 6;
    const int qlo = lane & 15, g = lane >> 4;
    const int idx = blk - NB;            // 0..23
    const int l = idx >> 3, dt = idx & 7;
    const bool isU = (dt < 4);
    const int dcol = (dt & 3) * 16 + qlo;

    const float* arow = emb + (wave * 16 + qlo) * ND;            // A row = object
    const float* brow = W1 + (l * ND + dcol) * 192 + (isU ? 0 : 64);
    f32x4 acc = {0.f, 0.f, 0.f, 0.f};
#pragma unroll
    for (int kh = 0; kh < 2; ++kh) {
      const int k0 = kh * 32 + g * 8;
      const bf16x8 af = pack_bf16(*(const f32x4*)(arow + k0), *(const f32x4*)(arow + k0 + 4));
      const bf16x8 bf = pack_bf16(*(const f32x4*)(brow + k0), *(const f32x4*)(brow + k0 + 4));
      acc = __builtin_amdgcn_mfma_f32_16x16x32_bf16(af, bf, acc, 0, 0, 0);
    }
    float* T = isU ? Ut : Vt;            // D: row(obj) = wave*16+4g+r, col(d) = dcol
#pragma unroll
    for (int r = 0; r < 4; ++r)
      T[(l * NO + wave * 16 + 4 * g + r) * ND + dcol] = acc[r];
  }
}

// ---------------------------------------------------------------------------
// Kernel 2: main (R7 structure — best known 43.2us). SINGLE CHANGE: fold the
// sigmoid prep into the MFMA. wfrag is pre-scaled by -log2e and the MFMA
// accumulator is initialized with -log2e*b2, so the MFMA emits
// y = -log2e*(logit+bias) directly and the epilogue is just
// rcp(1 + exp2(y)): 1 VALU + 2 trans per output (was 4 VALU + 2 trans).
// Theory: main_k is VALU-issue-bound (~96%), not write-bound.
// ---------------------------------------------------------------------------
__global__ __launch_bounds__(256, 6) void main_k(
    const int* __restrict__ ids, const float* __restrict__ W2,
    const float* __restrict__ b2,
    const float* __restrict__ Ut, const float* __restrict__ Vt,
    const float* __restrict__ M, float* __restrict__ out)
{
  __shared__ float UpM_s[16 * 68];

  const int tid = threadIdx.x, blk = blockIdx.x;
  const int ic = blk & 3, b = (blk >> 2) & 127, l = blk >> 9;
  const int lane = tid & 63, wave = tid >> 6;
  const int qlo = lane & 15, g = lane >> 4;
  const int i0 = ic * 16;

  // ---- stage UpM: 16 rows x 64 cols, one f32x4 per thread ----
  {
    const int row = tid >> 4, c0 = (tid & 15) * 4;
    const int idi = ids[b * NO + i0 + row];
    const float* u = Ut + (l * NO + idi) * ND + c0;
    const float* m = M + (l * NB + b) * ND + c0;
    *(f32x4*)(&UpM_s[row * 68 + c0]) = *(const f32x4*)u + *(const f32x4*)m;
  }

  // ---- V (f32), scaled W2 frags, scaled b2 into registers ----
  const int jA = wave * 16 + qlo;        // this lane's pair column j (fixed)
  const int idj = ids[b * NO + jA];
  const float* vrow = Vt + (l * NO + idj) * ND;
  f32x4 vf[2][2];
#pragma unroll
  for (int kt = 0; kt < 2; ++kt) {
    vf[kt][0] = *(const f32x4*)(vrow + kt * 32 + g * 8);
    vf[kt][1] = *(const f32x4*)(vrow + kt * 32 + g * 8 + 4);
  }
  bf16x8 wfrag[2][2];
#pragma unroll
  for (int qt = 0; qt < 2; ++qt)
#pragma unroll
    for (int kt = 0; kt < 2; ++kt) {
      const float* wp = W2 + (l * NQ + qt * 16 + qlo) * ND + kt * 32 + g * 8;
      wfrag[qt][kt] = pack_bf16_s(*(const f32x4*)wp, *(const f32x4*)(wp + 4), NLOG2E);
    }
  // MFMA C-init = -log2e * b2 (per-lane mapping r -> q = qt*16 + 4g + r)
  const f32x4 c0i = *(const f32x4*)(b2 + l * NQ + g * 4) * NLOG2E;
  const f32x4 c1i = *(const f32x4*)(b2 + l * NQ + 16 + g * 4) * NLOG2E;

  __syncthreads();

  float* outb = out + (size_t)(l * NB + b) * NP * NQ;

  // ---- barrier-free i-loop (unroll 2 for cross-iter ILP) ----
#pragma unroll 2
  for (int ii = 0; ii < 16; ++ii) {
    const float* upm = &UpM_s[ii * 68];
    bf16x8 hb[2];
#pragma unroll
    for (int kt = 0; kt < 2; ++kt) {
      const int k0 = kt * 32 + g * 8;
      const f32x4 r0 = *(const f32x4*)(upm + k0);
      const f32x4 r1 = *(const f32x4*)(upm + k0 + 4);
      f32x4 h0, h1;
#pragma unroll
      for (int e = 0; e < 4; ++e) {
        h0[e] = fmaxf(vf[kt][0][e] + r0[e], 0.0f);
        h1[e] = fmaxf(vf[kt][1][e] + r1[e], 0.0f);
      }
      hb[kt] = pack_bf16(h0, h1);
    }

    // acc = -log2e*(W2.H + b2); sigmoid = rcp(1 + exp2(acc))
    f32x4 acc0 = __builtin_amdgcn_mfma_f32_16x16x32_bf16(wfrag[0][0], hb[0], c0i, 0, 0, 0);
    acc0 = __builtin_amdgcn_mfma_f32_16x16x32_bf16(wfrag[0][1], hb[1], acc0, 0, 0, 0);
    f32x4 acc1 = __builtin_amdgcn_mfma_f32_16x16x32_bf16(wfrag[1][0], hb[0], c1i, 0, 0, 0);
    acc1 = __builtin_amdgcn_mfma_f32_16x16x32_bf16(wfrag[1][1], hb[1], acc1, 0, 0, 0);

    const int i = i0 + ii;
    if (jA != i) {
      const int p = (jA < i) ? jA : jA - 1;
      float* base = outb + ((size_t)i * 63 + p) * NQ + g * 4;
      f32x4 o0, o1;
#pragma unroll
      for (int r = 0; r < 4; ++r) {
        o0[r] = __builtin_amdgcn_rcpf(1.0f + __builtin_amdgcn_exp2f(acc0[r]));
        o1[r] = __builtin_amdgcn_rcpf(1.0f + __builtin_amdgcn_exp2f(acc1[r]));
      }
      *(f32x4*)base = o0;
      *(f32x4*)(base + 16) = o1;
    }
  }
}

// ---------------------------------------------------------------------------
extern "C" void kernel_launch(void* const* d_in, const int* in_sizes, int n_in,
                              void* d_out, int out_size, void* d_ws, size_t ws_size,
                              hipStream_t stream) {
  const int*   ids = (const int*)d_in[0];
  const float* emb = (const float*)d_in[1];
  const float* W1  = (const float*)d_in[2];
  const float* b1  = (const float*)d_in[3];
  const float* W2  = (const float*)d_in[4];
  const float* b2  = (const float*)d_in[5];
  float* out = (float*)d_out;

  float* Ut = (float*)d_ws;              // [3][64][64] f32
  float* Vt = Ut + NL * NO * ND;         // [3][64][64] f32
  float* M  = Vt + NL * NO * ND;         // [3][128][64] f32  (192 KB of ws)
  float* e_out = out + (size_t)NL * NB * NP * NQ;  // e appended after preds

  precomp_k<<<NB + 24, 256, 0, stream>>>(ids, emb, W1, b1, Ut, Vt, M, e_out);
  main_k<<<NL * NB * 4, 256, 0, stream>>>(ids, W2, b2, Ut, Vt, M, out);
}

// Round 11
// 42.626 us; speedup vs baseline: 1.1167x; 1.0280x over previous
//
#include <hip/hip_runtime.h>
#include <hip/hip_bf16.h>

// Sizes (fixed by the reference)
#define NL 3      // layers
#define NB 128    // batch
#define NO 64     // objects
#define ND 64     // emb dim
#define NQ 32     // preds per pair
#define NP 4032   // 64*63 ordered pairs

typedef __bf16 bf16x8 __attribute__((ext_vector_type(8)));
typedef float  f32x4  __attribute__((ext_vector_type(4)));

__device__ __forceinline__ float sigm(float x) {
  return __builtin_amdgcn_rcpf(1.0f + __expf(-x));
}

__device__ __forceinline__ bf16x8 pack_bf16(const f32x4 a, const f32x4 b) {
  bf16x8 r;
  r[0] = (__bf16)a[0]; r[1] = (__bf16)a[1]; r[2] = (__bf16)a[2]; r[3] = (__bf16)a[3];
  r[4] = (__bf16)b[0]; r[5] = (__bf16)b[1]; r[6] = (__bf16)b[2]; r[7] = (__bf16)b[3];
  return r;
}

// ---------------------------------------------------------------------------
// Kernel 1: precompute (verbatim round 7 — known good).
//   blocks 0..127   : b -> mean, M[l][b][d] = mean.W1c + b1 ; exact e copy
//   blocks 128..151 : (l, dt) -> one 64x16 strip of Ut/Vt via MFMA
// ---------------------------------------------------------------------------
__global__ __launch_bounds__(256) void precomp_k(
    const int* __restrict__ ids, const float* __restrict__ emb,
    const float* __restrict__ W1, const float* __restrict__ b1,
    float* __restrict__ Ut, float* __restrict__ Vt, float* __restrict__ M,
    float* __restrict__ e_out)
{
  const int blk = blockIdx.x, tid = threadIdx.x;

  if (blk < NB) {
    __shared__ int   ids_s[NO];
    __shared__ float psum[4][ND];
    __shared__ float mean_s[ND];
    const int b = blk;
    if (tid < NO) ids_s[tid] = ids[b * NO + tid];
    __syncthreads();

    {
      const int d = tid & 63, ng = tid >> 6;
      float s = 0.f;
#pragma unroll
      for (int nn = 0; nn < 16; ++nn) {
        const int n = ng * 16 + nn;
        const float v = emb[ids_s[n] * ND + d];
        e_out[(b * NO + n) * ND + d] = v;   // exact f32 copy of e
        s += v;
      }
      psum[ng][d] = s;
    }
    __syncthreads();
    if (tid < ND)
      mean_s[tid] = (psum[0][tid] + psum[1][tid] + psum[2][tid] + psum[3][tid]) * (1.0f / 64.0f);
    __syncthreads();

    if (tid < 192) {
      const int l = tid >> 6, d = tid & 63;
      const float* wrow = W1 + (l * ND + d) * 192 + 128;
      float acc = 0.f;
#pragma unroll
      for (int c4 = 0; c4 < 16; ++c4) {
        const f32x4 w = *(const f32x4*)(wrow + c4 * 4);
        const f32x4 m = *(const f32x4*)(&mean_s[c4 * 4]);
        acc += w[0] * m[0] + w[1] * m[1] + w[2] * m[2] + w[3] * m[3];
      }
      M[(l * NB + b) * ND + d] = acc + b1[l * ND + d];
    }
  } else {
    // ---- table blocks: one (l, d-tile) strip per block, one row-tile/wave ----
    const int lane = tid & 63, wave = tid >> 6;
    const int qlo = lane & 15, g = lane >> 4;
    const int idx = blk - NB;            // 0..23
    const int l = idx >> 3, dt = idx & 7;
    const bool isU = (dt < 4);
    const int dcol = (dt & 3) * 16 + qlo;

    const float* arow = emb + (wave * 16 + qlo) * ND;            // A row = object
    const float* brow = W1 + (l * ND + dcol) * 192 + (isU ? 0 : 64);
    f32x4 acc = {0.f, 0.f, 0.f, 0.f};
#pragma unroll
    for (int kh = 0; kh < 2; ++kh) {
      const int k0 = kh * 32 + g * 8;
      const bf16x8 af = pack_bf16(*(const f32x4*)(arow + k0), *(const f32x4*)(arow + k0 + 4));
      const bf16x8 bf = pack_bf16(*(const f32x4*)(brow + k0), *(const f32x4*)(brow + k0 + 4));
      acc = __builtin_amdgcn_mfma_f32_16x16x32_bf16(af, bf, acc, 0, 0, 0);
    }
    float* T = isU ? Ut : Vt;            // D: row(obj) = wave*16+4g+r, col(d) = dcol
#pragma unroll
    for (int r = 0; r < 4; ++r)
      T[(l * NO + wave * 16 + 4 * g + r) * ND + dcol] = acc[r];
  }
}

// ---------------------------------------------------------------------------
// Kernel 2: main (R7 structure — best known 43.2us). SINGLE CHANGE: bijective
// XCD-aware block swizzle. Block->output mapping is linear in wg, so
// wg = (blk&7)*192 + blk>>3 gives each XCD one contiguous ~24.8MB output
// slab -> per-XCD L2 dirty evictions stream contiguously to HBM
// (fill-kernel-like write locality), instead of 129KB chunks scattered
// across the whole 198MB.
// ---------------------------------------------------------------------------
__global__ __launch_bounds__(256, 6) void main_k(
    const int* __restrict__ ids, const float* __restrict__ W2,
    const float* __restrict__ b2,
    const float* __restrict__ Ut, const float* __restrict__ Vt,
    const float* __restrict__ M, float* __restrict__ out)
{
  __shared__ float UpM_s[16 * 68];

  const int tid = threadIdx.x;
  // XCD swizzle: nwg = 1536 = 8 * 192, exact -> bijective
  const int wg = (blockIdx.x & 7) * 192 + (blockIdx.x >> 3);
  const int ic = wg & 3, b = (wg >> 2) & 127, l = wg >> 9;
  const int lane = tid & 63, wave = tid >> 6;
  const int qlo = lane & 15, g = lane >> 4;
  const int i0 = ic * 16;

  // ---- stage UpM: 16 rows x 64 cols, one f32x4 per thread ----
  {
    const int row = tid >> 4, c0 = (tid & 15) * 4;
    const int idi = ids[b * NO + i0 + row];
    const float* u = Ut + (l * NO + idi) * ND + c0;
    const float* m = M + (l * NB + b) * ND + c0;
    *(f32x4*)(&UpM_s[row * 68 + c0]) = *(const f32x4*)u + *(const f32x4*)m;
  }

  // ---- V (f32), W2 frags, b2 into registers (loop-invariant) ----
  const int jA = wave * 16 + qlo;        // this lane's pair column j (fixed)
  const int idj = ids[b * NO + jA];
  const float* vrow = Vt + (l * NO + idj) * ND;
  f32x4 vf[2][2];
#pragma unroll
  for (int kt = 0; kt < 2; ++kt) {
    vf[kt][0] = *(const f32x4*)(vrow + kt * 32 + g * 8);
    vf[kt][1] = *(const f32x4*)(vrow + kt * 32 + g * 8 + 4);
  }
  bf16x8 wfrag[2][2];
#pragma unroll
  for (int qt = 0; qt < 2; ++qt)
#pragma unroll
    for (int kt = 0; kt < 2; ++kt) {
      const float* wp = W2 + (l * NQ + qt * 16 + qlo) * ND + kt * 32 + g * 8;
      wfrag[qt][kt] = pack_bf16(*(const f32x4*)wp, *(const f32x4*)(wp + 4));
    }
  const f32x4 b20 = *(const f32x4*)(b2 + l * NQ + g * 4);        // q = 4g+r
  const f32x4 b21 = *(const f32x4*)(b2 + l * NQ + 16 + g * 4);   // q = 16+4g+r

  __syncthreads();

  float* outb = out + (size_t)(l * NB + b) * NP * NQ;

  // ---- barrier-free i-loop (unroll 2 for cross-iter ILP) ----
#pragma unroll 2
  for (int ii = 0; ii < 16; ++ii) {
    const float* upm = &UpM_s[ii * 68];
    bf16x8 hb[2];
#pragma unroll
    for (int kt = 0; kt < 2; ++kt) {
      const int k0 = kt * 32 + g * 8;
      const f32x4 r0 = *(const f32x4*)(upm + k0);
      const f32x4 r1 = *(const f32x4*)(upm + k0 + 4);
      f32x4 h0, h1;
#pragma unroll
      for (int e = 0; e < 4; ++e) {
        h0[e] = fmaxf(vf[kt][0][e] + r0[e], 0.0f);
        h1[e] = fmaxf(vf[kt][1][e] + r1[e], 0.0f);
      }
      hb[kt] = pack_bf16(h0, h1);
    }

    const f32x4 z = {0.f, 0.f, 0.f, 0.f};
    // Swapped operands: D[row=q][col=j]; lane holds q = 4g+r, j = qlo+wave*16
    f32x4 acc0 = __builtin_amdgcn_mfma_f32_16x16x32_bf16(wfrag[0][0], hb[0], z, 0, 0, 0);
    acc0 = __builtin_amdgcn_mfma_f32_16x16x32_bf16(wfrag[0][1], hb[1], acc0, 0, 0, 0);
    f32x4 acc1 = __builtin_amdgcn_mfma_f32_16x16x32_bf16(wfrag[1][0], hb[0], z, 0, 0, 0);
    acc1 = __builtin_amdgcn_mfma_f32_16x16x32_bf16(wfrag[1][1], hb[1], acc1, 0, 0, 0);

    const int i = i0 + ii;
    if (jA != i) {
      const int p = (jA < i) ? jA : jA - 1;
      float* base = outb + ((size_t)i * 63 + p) * NQ + g * 4;
      f32x4 o0, o1;
#pragma unroll
      for (int r = 0; r < 4; ++r) {
        o0[r] = sigm(acc0[r] + b20[r]);
        o1[r] = sigm(acc1[r] + b21[r]);
      }
      *(f32x4*)base = o0;
      *(f32x4*)(base + 16) = o1;
    }
  }
}

// ---------------------------------------------------------------------------
extern "C" void kernel_launch(void* const* d_in, const int* in_sizes, int n_in,
                              void* d_out, int out_size, void* d_ws, size_t ws_size,
                              hipStream_t stream) {
  const int*   ids = (const int*)d_in[0];
  const float* emb = (const float*)d_in[1];
  const float* W1  = (const float*)d_in[2];
  const float* b1  = (const float*)d_in[3];
  const float* W2  = (const float*)d_in[4];
  const float* b2  = (const float*)d_in[5];
  float* out = (float*)d_out;

  float* Ut = (float*)d_ws;              // [3][64][64] f32
  float* Vt = Ut + NL * NO * ND;         // [3][64][64] f32
  float* M  = Vt + NL * NO * ND;         // [3][128][64] f32  (192 KB of ws)
  float* e_out = out + (size_t)NL * NB * NP * NQ;  // e appended after preds

  precomp_k<<<NB + 24, 256, 0, stream>>>(ids, emb, W1, b1, Ut, Vt, M, e_out);
  main_k<<<NL * NB * 4, 256, 0, stream>>>(ids, W2, b2, Ut, Vt, M, out);
}